// Round 3
// baseline (207.421 us; speedup 1.0000x reference)
//
#include <hip/hip_runtime.h>
#include <hip/hip_fp16.h>
#include <math.h>

#define HH 384
#define WW 384
#define CNUM 64
#define BNUM 4
#define HWSZ (HH*WW)
#define NPLANES (BNUM*CNUM)              // 256
#define EPSBN 1e-5f

// K1 geometry
#define ROWS_K1 32
#define BPP_K1 (HH/ROWS_K1)              // 12 blocks per plane
#define NB_K1 (NPLANES*BPP_K1)           // 3072
// fallback geometry
#define ROWS_FB 16
#define BPP_FB (HH/ROWS_FB)              // 24
#define NB_FB (NPLANES*BPP_FB)           // 6144

typedef float f4v __attribute__((ext_vector_type(4)));

// ---- stencil: 17 loads then eval ----
__device__ __forceinline__ void pcm_loads(const float* __restrict__ pp, int h, int w,
      int wp13, int wm13, int wp17, int wm17, float* v)
{
  int hp13 = h+13; if (hp13 >= HH) hp13 -= HH;
  int hm13 = h-13; if (hm13 <  0 ) hm13 += HH;
  int hp17 = h+17; if (hp17 >= HH) hp17 -= HH;
  int hm17 = h-17; if (hm17 <  0 ) hm17 += HH;
  const float* r0   = pp + h*WW;
  const float* rp13 = pp + hp13*WW;
  const float* rm13 = pp + hm13*WW;
  const float* rp17 = pp + hp17*WW;
  const float* rm17 = pp + hm17*WW;
  v[0]  = r0[w];
  v[1]  = rp13[wp13]; v[2]  = rm13[wm13];
  v[3]  = rp13[w];    v[4]  = rm13[w];
  v[5]  = rp13[wm13]; v[6]  = rm13[wp13];
  v[7]  = r0[wm13];   v[8]  = r0[wp13];
  v[9]  = rp17[wp17]; v[10] = rm17[wm17];
  v[11] = rp17[w];    v[12] = rm17[w];
  v[13] = rp17[wm17]; v[14] = rm17[wp17];
  v[15] = r0[wm17];   v[16] = r0[wp17];
}

__device__ __forceinline__ void pcm_eval(const float* v, float& p13, float& p17)
{
  const float d = v[0];
  {
    float s1 = (v[1]-d)*(v[2]-d);
    float s2 = (v[3]-d)*(v[4]-d);
    float s3 = (v[5]-d)*(v[6]-d);
    float s4 = (v[7]-d)*(v[8]-d);
    p13 = fminf(fminf(s1,s2), fminf(s3,s4));
  }
  {
    float s1 = (v[9] -d)*(v[10]-d);
    float s2 = (v[11]-d)*(v[12]-d);
    float s3 = (v[13]-d)*(v[14]-d);
    float s4 = (v[15]-d)*(v[16]-d);
    p17 = fminf(fminf(s1,s2), fminf(s3,s4));
  }
}

// XCD-aware chunked swizzle (NB divisible by 8): all blocks of a plane on one XCD
template<int NB>
__device__ __forceinline__ int swz_block() {
  return (blockIdx.x & 7)*(NB/8) + (blockIdx.x >> 3);
}

// ---- K1: stencil once -> pack half2 to ws + BN partials ----
__global__ __launch_bounds__(384) void k1_kernel(const float* __restrict__ cen,
                                                 unsigned int* __restrict__ pcm_ws,
                                                 float* __restrict__ partials)
{
  const int blk = swz_block<NB_K1>();
  const int p   = blk / BPP_K1;
  const int kb  = blk % BPP_K1;
  const int w   = threadIdx.x;               // 0..383
  const float* pp = cen + (size_t)p*HWSZ;
  unsigned int* wp = pcm_ws + (size_t)p*HWSZ;

  int wp13 = w+13; if (wp13 >= WW) wp13 -= WW;
  int wm13 = w-13; if (wm13 <  0 ) wm13 += WW;
  int wp17 = w+17; if (wp17 >= WW) wp17 -= WW;
  int wm17 = w-17; if (wm17 <  0 ) wm17 += WW;

  float s13 = 0.f, q13 = 0.f, s17 = 0.f, q17 = 0.f;
  const int h0 = kb*ROWS_K1;
  #pragma unroll 4
  for (int r = 0; r < ROWS_K1; ++r) {
    const int h = h0 + r;
    float v[17];
    pcm_loads(pp, h, w, wp13, wm13, wp17, wm17, v);
    float p13, p17;
    pcm_eval(v, p13, p17);
    __half2 hp = __floats2half2_rn(p13, p17);
    wp[h*WW + w] = *reinterpret_cast<unsigned int*>(&hp);
    // accumulate the ROUNDED values (consistent with final pass)
    float2 fr = __half22float2(hp);
    s13 += fr.x; q13 += fr.x*fr.x;
    s17 += fr.y; q17 += fr.y*fr.y;
  }
  for (int off = 32; off > 0; off >>= 1) {
    s13 += __shfl_down(s13, off);
    q13 += __shfl_down(q13, off);
    s17 += __shfl_down(s17, off);
    q17 += __shfl_down(q17, off);
  }
  __shared__ float red[6][4];
  const int wid = threadIdx.x >> 6;
  if ((threadIdx.x & 63) == 0) {
    red[wid][0] = s13; red[wid][1] = q13; red[wid][2] = s17; red[wid][3] = q17;
  }
  __syncthreads();
  if (threadIdx.x == 0) {
    float a=0.f,b=0.f,c=0.f,d=0.f;
    for (int i = 0; i < 6; ++i) { a+=red[i][0]; b+=red[i][1]; c+=red[i][2]; d+=red[i][3]; }
    float* q = partials + (size_t)blk*4;
    q[0]=a; q[1]=b; q[2]=c; q[3]=d;
  }
}

// ---- SE MLP helper (256 threads) ----
__device__ void se_mlp(int t, const float* __restrict__ p,
    const float* __restrict__ w1, const float* __restrict__ b1,
    const float* __restrict__ g1, const float* __restrict__ be1,
    const float* __restrict__ w2, const float* __restrict__ b2,
    const float* __restrict__ g2, const float* __restrict__ be2,
    float* y1, float* sc, float* sh, float* wei)
{
  if (t < 128) {
    const int b = t >> 5, o = t & 31;
    float acc = b1[o];
    const float* wr = w1 + o*64;
    const float* pr = p  + b*64;
    #pragma unroll
    for (int c = 0; c < 64; ++c) acc += wr[c]*pr[c];
    y1[t] = acc;
  }
  __syncthreads();
  if (t < 32) {
    float a0=y1[t], a1=y1[32+t], a2=y1[64+t], a3=y1[96+t];
    float m = 0.25f*(a0+a1+a2+a3);
    float q = 0.25f*(a0*a0+a1*a1+a2*a2+a3*a3);
    float v = q - m*m;
    float s = g1[t]*rsqrtf(v + EPSBN);
    sc[t] = s; sh[t] = be1[t] - m*s;
  }
  __syncthreads();
  if (t < 128) {
    const int o = t & 31;
    y1[t] = fmaxf(y1[t]*sc[o] + sh[o], 0.0f);
  }
  __syncthreads();
  {
    const int b = t >> 6, o2 = t & 63;
    float acc = b2[o2];
    const float* wr = w2 + o2*32;
    const float* yr = y1 + b*32;
    #pragma unroll
    for (int o = 0; o < 32; ++o) acc += wr[o]*yr[o];
    wei[t] = acc;
  }
  __syncthreads();
  if (t < 64) {
    float a0=wei[t], a1=wei[64+t], a2=wei[128+t], a3=wei[192+t];
    float m = 0.25f*(a0+a1+a2+a3);
    float q = 0.25f*(a0*a0+a1*a1+a2*a2+a3*a3);
    float v = q - m*m;
    float s = g2[t]*rsqrtf(v + EPSBN);
    sc[t] = s; sh[t] = be2[t] - m*s;
  }
  __syncthreads();
  {
    const int o2 = t & 63;
    float z = wei[t]*sc[o2] + sh[o2];
    wei[t] = 1.0f/(1.0f + expf(-z));
  }
  __syncthreads();
}

// ---- K2: partials -> BN stats -> SE MLPs -> per-plane coefficients ----
__global__ __launch_bounds__(256) void se_kernel(
    const float* __restrict__ partials, int bpp,
    const float* __restrict__ bn1_g, const float* __restrict__ bn1_b,
    const float* __restrict__ bn2_g, const float* __restrict__ bn2_b,
    const float* __restrict__ td_w1, const float* __restrict__ td_b1,
    const float* __restrict__ td_g1, const float* __restrict__ td_be1,
    const float* __restrict__ td_w2, const float* __restrict__ td_b2,
    const float* __restrict__ td_g2, const float* __restrict__ td_be2,
    const float* __restrict__ bu_w1, const float* __restrict__ bu_b1,
    const float* __restrict__ bu_g1, const float* __restrict__ bu_be1,
    const float* __restrict__ bu_w2, const float* __restrict__ bu_b2,
    const float* __restrict__ bu_g2, const float* __restrict__ bu_be2,
    float* __restrict__ coef)
{
  __shared__ float sum13[256], sq13[256], sum17[256], sq17[256];
  __shared__ float scale1[64], shift1[64], scale2[64], shift2[64];
  __shared__ float pm13[256], pm17[256];
  __shared__ float y1[128], sc[64], sh[64];
  __shared__ float tdw[256], buw[256];
  const int t = threadIdx.x;

  {
    float a=0.f,b=0.f,c=0.f,d=0.f;
    for (int kb = 0; kb < bpp; ++kb) {
      const float* q = partials + ((size_t)(t*bpp + kb))*4;
      a += q[0]; b += q[1]; c += q[2]; d += q[3];
    }
    sum13[t]=a; sq13[t]=b; sum17[t]=c; sq17[t]=d;
  }
  __syncthreads();

  if (t < 64) {
    float s=0.f,q=0.f,s2=0.f,q2=0.f;
    for (int b = 0; b < 4; ++b) {
      s  += sum13[b*64+t]; q  += sq13[b*64+t];
      s2 += sum17[b*64+t]; q2 += sq17[b*64+t];
    }
    const float inv = 1.0f/(4.0f*HWSZ);
    float m1 = s*inv,  v1 = q*inv  - m1*m1;
    float c1 = bn1_g[t]*rsqrtf(v1 + EPSBN);
    scale1[t] = c1; shift1[t] = bn1_b[t] - m1*c1;
    float m2 = s2*inv, v2 = q2*inv - m2*m2;
    float c2 = bn2_g[t]*rsqrtf(v2 + EPSBN);
    scale2[t] = c2; shift2[t] = bn2_b[t] - m2*c2;
  }
  __syncthreads();

  {
    const int c = t & 63;
    pm13[t] = (sum13[t]*(1.0f/HWSZ))*scale1[c] + shift1[c];
    pm17[t] = (sum17[t]*(1.0f/HWSZ))*scale2[c] + shift2[c];
  }
  __syncthreads();

  se_mlp(t, pm17, td_w1, td_b1, td_g1, td_be1, td_w2, td_b2, td_g2, td_be2, y1, sc, sh, tdw);
  se_mlp(t, pm13, bu_w1, bu_b1, bu_g1, bu_be1, bu_w2, bu_b2, bu_g2, bu_be2, y1, sc, sh, buw);

  {
    const int c = t & 63;
    float A  = tdw[t]*scale1[c];
    float Bc = buw[t]*scale2[c];
    float Cc = tdw[t]*shift1[c] + buw[t]*shift2[c];
    coef[t*4+0] = A; coef[t*4+1] = Bc; coef[t*4+2] = Cc; coef[t*4+3] = 0.f;
  }
}

// ---- K3: elementwise combine from packed pcm ----
#define K3_BLOCKS 4608
#define K3_THREADS 256
typedef unsigned int u4v __attribute__((ext_vector_type(4)));

__global__ __launch_bounds__(K3_THREADS) void k3_kernel(const u4v* __restrict__ pcm4,
                                                        const f4v* __restrict__ coef4,
                                                        f4v* __restrict__ out4)
{
  const int total = NPLANES*HWSZ/4;           // 9,437,184
  int i = blockIdx.x*K3_THREADS + threadIdx.x;
  const int stride = K3_BLOCKS*K3_THREADS;
  for (; i < total; i += stride) {
    const int plane = (i*4)/HWSZ;             // 4 px always within one plane
    const f4v cf = coef4[plane];              // A,B,C,_
    const u4v v = pcm4[i];
    f4v o;
    #pragma unroll
    for (int j = 0; j < 4; ++j) {
      unsigned int u = v[j];
      __half2 hp = *reinterpret_cast<__half2*>(&u);
      float2 f = __half22float2(hp);
      o[j] = cf.x*f.x + cf.y*f.y + cf.z;
    }
    __builtin_nontemporal_store(o, &out4[i]);
  }
}

// ================= fallback (small ws): round-2 scheme =================
__global__ __launch_bounds__(384) void passA_kernel(const float* __restrict__ cen,
                                                    float* __restrict__ partials)
{
  const int blk = swz_block<NB_FB>();
  const int p   = blk / BPP_FB;
  const int kb  = blk % BPP_FB;
  const int w   = threadIdx.x;
  const float* pp = cen + (size_t)p*HWSZ;

  int wp13 = w+13; if (wp13 >= WW) wp13 -= WW;
  int wm13 = w-13; if (wm13 <  0 ) wm13 += WW;
  int wp17 = w+17; if (wp17 >= WW) wp17 -= WW;
  int wm17 = w-17; if (wm17 <  0 ) wm17 += WW;

  float s13 = 0.f, q13 = 0.f, s17 = 0.f, q17 = 0.f;
  const int h0 = kb*ROWS_FB;
  #pragma unroll 4
  for (int r = 0; r < ROWS_FB; ++r) {
    float v[17];
    pcm_loads(pp, h0+r, w, wp13, wm13, wp17, wm17, v);
    float a13, a17;
    pcm_eval(v, a13, a17);
    s13 += a13; q13 += a13*a13;
    s17 += a17; q17 += a17*a17;
  }
  for (int off = 32; off > 0; off >>= 1) {
    s13 += __shfl_down(s13, off);
    q13 += __shfl_down(q13, off);
    s17 += __shfl_down(s17, off);
    q17 += __shfl_down(q17, off);
  }
  __shared__ float red[6][4];
  const int wid = threadIdx.x >> 6;
  if ((threadIdx.x & 63) == 0) {
    red[wid][0] = s13; red[wid][1] = q13; red[wid][2] = s17; red[wid][3] = q17;
  }
  __syncthreads();
  if (threadIdx.x == 0) {
    float a=0.f,b=0.f,c=0.f,d=0.f;
    for (int i = 0; i < 6; ++i) { a+=red[i][0]; b+=red[i][1]; c+=red[i][2]; d+=red[i][3]; }
    float* q = partials + (size_t)blk*4;
    q[0]=a; q[1]=b; q[2]=c; q[3]=d;
  }
}

__global__ __launch_bounds__(384) void passB_kernel(const float* __restrict__ cen,
                                                    const float* __restrict__ coef,
                                                    float* __restrict__ out)
{
  const int blk = swz_block<NB_FB>();
  const int p   = blk / BPP_FB;
  const int kb  = blk % BPP_FB;
  const int w   = threadIdx.x;
  const float A  = coef[p*4+0];
  const float Bc = coef[p*4+1];
  const float Cc = coef[p*4+2];
  const float* pp = cen + (size_t)p*HWSZ;
  float* op = out + (size_t)p*HWSZ;

  int wp13 = w+13; if (wp13 >= WW) wp13 -= WW;
  int wm13 = w-13; if (wm13 <  0 ) wm13 += WW;
  int wp17 = w+17; if (wp17 >= WW) wp17 -= WW;
  int wm17 = w-17; if (wm17 <  0 ) wm17 += WW;

  const int h0 = kb*ROWS_FB;
  #pragma unroll 4
  for (int r = 0; r < ROWS_FB; ++r) {
    const int h = h0 + r;
    float v[17];
    pcm_loads(pp, h, w, wp13, wm13, wp17, wm17, v);
    float a13, a17;
    pcm_eval(v, a13, a17);
    __builtin_nontemporal_store(A*a13 + Bc*a17 + Cc, &op[h*WW + w]);
  }
}

extern "C" void kernel_launch(void* const* d_in, const int* in_sizes, int n_in,
                              void* d_out, int out_size, void* d_ws, size_t ws_size,
                              hipStream_t stream) {
  const float* cen = (const float*)d_in[0];
  const size_t PCM_BYTES = (size_t)NPLANES*HWSZ*sizeof(unsigned int);   // ~151 MB
  const size_t NEED = PCM_BYTES + (size_t)NB_K1*4*sizeof(float) + 256*4*sizeof(float);

  if (ws_size >= NEED) {
    unsigned int* pcm_ws = (unsigned int*)d_ws;
    float* partials = (float*)((char*)d_ws + PCM_BYTES);
    float* coef     = partials + (size_t)NB_K1*4;

    k1_kernel<<<NB_K1, 384, 0, stream>>>(cen, pcm_ws, partials);
    se_kernel<<<1, 256, 0, stream>>>(partials, BPP_K1,
        (const float*)d_in[1],  (const float*)d_in[2],  (const float*)d_in[3],  (const float*)d_in[4],
        (const float*)d_in[5],  (const float*)d_in[6],  (const float*)d_in[7],  (const float*)d_in[8],
        (const float*)d_in[9],  (const float*)d_in[10], (const float*)d_in[11], (const float*)d_in[12],
        (const float*)d_in[13], (const float*)d_in[14], (const float*)d_in[15], (const float*)d_in[16],
        (const float*)d_in[17], (const float*)d_in[18], (const float*)d_in[19], (const float*)d_in[20],
        coef);
    k3_kernel<<<K3_BLOCKS, K3_THREADS, 0, stream>>>((const u4v*)pcm_ws, (const f4v*)coef, (f4v*)d_out);
  } else {
    float* ws = (float*)d_ws;
    float* partials = ws;
    float* coef     = ws + (size_t)NB_FB*4;
    passA_kernel<<<NB_FB, 384, 0, stream>>>(cen, partials);
    se_kernel<<<1, 256, 0, stream>>>(partials, BPP_FB,
        (const float*)d_in[1],  (const float*)d_in[2],  (const float*)d_in[3],  (const float*)d_in[4],
        (const float*)d_in[5],  (const float*)d_in[6],  (const float*)d_in[7],  (const float*)d_in[8],
        (const float*)d_in[9],  (const float*)d_in[10], (const float*)d_in[11], (const float*)d_in[12],
        (const float*)d_in[13], (const float*)d_in[14], (const float*)d_in[15], (const float*)d_in[16],
        (const float*)d_in[17], (const float*)d_in[18], (const float*)d_in[19], (const float*)d_in[20],
        coef);
    passB_kernel<<<NB_FB, 384, 0, stream>>>(cen, coef, (float*)d_out);
  }
}

// Round 4
// 167.561 us; speedup vs baseline: 1.2379x; 1.2379x over previous
//
#include <hip/hip_runtime.h>
#include <hip/hip_fp16.h>
#include <math.h>

#define HH 384
#define WW 384
#define CNUM 64
#define BNUM 4
#define HWSZ (HH*WW)
#define NPLANES (BNUM*CNUM)              // 256
#define EPSBN 1e-5f

// K1 geometry
#define ROWS_K1 32
#define BPP_K1 (HH/ROWS_K1)              // 12 blocks per plane
#define NB_K1 (NPLANES*BPP_K1)           // 3072
// fallback geometry
#define ROWS_FB 16
#define BPP_FB (HH/ROWS_FB)              // 24
#define NB_FB (NPLANES*BPP_FB)           // 6144

typedef float f4v __attribute__((ext_vector_type(4)));
typedef unsigned int u4v __attribute__((ext_vector_type(4)));

// ---- stencil: 17 loads then eval ----
__device__ __forceinline__ void pcm_loads(const float* __restrict__ pp, int h, int w,
      int wp13, int wm13, int wp17, int wm17, float* v)
{
  int hp13 = h+13; if (hp13 >= HH) hp13 -= HH;
  int hm13 = h-13; if (hm13 <  0 ) hm13 += HH;
  int hp17 = h+17; if (hp17 >= HH) hp17 -= HH;
  int hm17 = h-17; if (hm17 <  0 ) hm17 += HH;
  const float* r0   = pp + h*WW;
  const float* rp13 = pp + hp13*WW;
  const float* rm13 = pp + hm13*WW;
  const float* rp17 = pp + hp17*WW;
  const float* rm17 = pp + hm17*WW;
  v[0]  = r0[w];
  v[1]  = rp13[wp13]; v[2]  = rm13[wm13];
  v[3]  = rp13[w];    v[4]  = rm13[w];
  v[5]  = rp13[wm13]; v[6]  = rm13[wp13];
  v[7]  = r0[wm13];   v[8]  = r0[wp13];
  v[9]  = rp17[wp17]; v[10] = rm17[wm17];
  v[11] = rp17[w];    v[12] = rm17[w];
  v[13] = rp17[wm17]; v[14] = rm17[wp17];
  v[15] = r0[wm17];   v[16] = r0[wp17];
}

__device__ __forceinline__ void pcm_eval(const float* v, float& p13, float& p17)
{
  const float d = v[0];
  {
    float s1 = (v[1]-d)*(v[2]-d);
    float s2 = (v[3]-d)*(v[4]-d);
    float s3 = (v[5]-d)*(v[6]-d);
    float s4 = (v[7]-d)*(v[8]-d);
    p13 = fminf(fminf(s1,s2), fminf(s3,s4));
  }
  {
    float s1 = (v[9] -d)*(v[10]-d);
    float s2 = (v[11]-d)*(v[12]-d);
    float s3 = (v[13]-d)*(v[14]-d);
    float s4 = (v[15]-d)*(v[16]-d);
    p17 = fminf(fminf(s1,s2), fminf(s3,s4));
  }
}

// XCD-aware chunked swizzle (NB divisible by 8)
template<int NB>
__device__ __forceinline__ int swz_block() {
  return (blockIdx.x & 7)*(NB/8) + (blockIdx.x >> 3);
}

// ---- K1: stencil once -> pack half2 (NT) + BN partials ----
// 2-row load batches with a sched_barrier so all 34 loads are in flight
// before the first consume (defeats the low-pressure scheduler).
__global__ __launch_bounds__(384) void k1_kernel(const float* __restrict__ cen,
                                                 unsigned int* __restrict__ pcm_ws,
                                                 float* __restrict__ partials)
{
  const int blk = swz_block<NB_K1>();
  const int p   = blk / BPP_K1;
  const int kb  = blk % BPP_K1;
  const int w   = threadIdx.x;               // 0..383
  const float* pp = cen + (size_t)p*HWSZ;
  unsigned int* wp = pcm_ws + (size_t)p*HWSZ;

  int wp13 = w+13; if (wp13 >= WW) wp13 -= WW;
  int wm13 = w-13; if (wm13 <  0 ) wm13 += WW;
  int wp17 = w+17; if (wp17 >= WW) wp17 -= WW;
  int wm17 = w-17; if (wm17 <  0 ) wm17 += WW;

  float s13 = 0.f, q13 = 0.f, s17 = 0.f, q17 = 0.f;
  const int h0 = kb*ROWS_K1;
  for (int r = 0; r < ROWS_K1; r += 2) {
    const int h = h0 + r;
    float va[17], vb[17];
    pcm_loads(pp, h,   w, wp13, wm13, wp17, wm17, va);
    pcm_loads(pp, h+1, w, wp13, wm13, wp17, wm17, vb);
    __builtin_amdgcn_sched_barrier(0);       // keep all 34 loads issued first
    float a13, a17, b13, b17;
    pcm_eval(va, a13, a17);
    pcm_eval(vb, b13, b17);
    __half2 ha = __floats2half2_rn(a13, a17);
    __half2 hb = __floats2half2_rn(b13, b17);
    __builtin_nontemporal_store(*reinterpret_cast<unsigned int*>(&ha), &wp[h*WW + w]);
    __builtin_nontemporal_store(*reinterpret_cast<unsigned int*>(&hb), &wp[(h+1)*WW + w]);
    float2 fa = __half22float2(ha);
    float2 fb = __half22float2(hb);
    s13 += fa.x + fb.x; q13 += fa.x*fa.x + fb.x*fb.x;
    s17 += fa.y + fb.y; q17 += fa.y*fa.y + fb.y*fb.y;
  }
  for (int off = 32; off > 0; off >>= 1) {
    s13 += __shfl_down(s13, off);
    q13 += __shfl_down(q13, off);
    s17 += __shfl_down(s17, off);
    q17 += __shfl_down(q17, off);
  }
  __shared__ float red[6][4];
  const int wid = threadIdx.x >> 6;
  if ((threadIdx.x & 63) == 0) {
    red[wid][0] = s13; red[wid][1] = q13; red[wid][2] = s17; red[wid][3] = q17;
  }
  __syncthreads();
  if (threadIdx.x == 0) {
    float a=0.f,b=0.f,c=0.f,d=0.f;
    for (int i = 0; i < 6; ++i) { a+=red[i][0]; b+=red[i][1]; c+=red[i][2]; d+=red[i][3]; }
    float* q = partials + (size_t)blk*4;
    q[0]=a; q[1]=b; q[2]=c; q[3]=d;
  }
}

// ---- SE MLP helper (256 threads) ----
__device__ void se_mlp(int t, const float* __restrict__ p,
    const float* __restrict__ w1, const float* __restrict__ b1,
    const float* __restrict__ g1, const float* __restrict__ be1,
    const float* __restrict__ w2, const float* __restrict__ b2,
    const float* __restrict__ g2, const float* __restrict__ be2,
    float* y1, float* sc, float* sh, float* wei)
{
  if (t < 128) {
    const int b = t >> 5, o = t & 31;
    float acc = b1[o];
    const float* wr = w1 + o*64;
    const float* pr = p  + b*64;
    #pragma unroll
    for (int c = 0; c < 64; ++c) acc += wr[c]*pr[c];
    y1[t] = acc;
  }
  __syncthreads();
  if (t < 32) {
    float a0=y1[t], a1=y1[32+t], a2=y1[64+t], a3=y1[96+t];
    float m = 0.25f*(a0+a1+a2+a3);
    float q = 0.25f*(a0*a0+a1*a1+a2*a2+a3*a3);
    float v = q - m*m;
    float s = g1[t]*rsqrtf(v + EPSBN);
    sc[t] = s; sh[t] = be1[t] - m*s;
  }
  __syncthreads();
  if (t < 128) {
    const int o = t & 31;
    y1[t] = fmaxf(y1[t]*sc[o] + sh[o], 0.0f);
  }
  __syncthreads();
  {
    const int b = t >> 6, o2 = t & 63;
    float acc = b2[o2];
    const float* wr = w2 + o2*32;
    const float* yr = y1 + b*32;
    #pragma unroll
    for (int o = 0; o < 32; ++o) acc += wr[o]*yr[o];
    wei[t] = acc;
  }
  __syncthreads();
  if (t < 64) {
    float a0=wei[t], a1=wei[64+t], a2=wei[128+t], a3=wei[192+t];
    float m = 0.25f*(a0+a1+a2+a3);
    float q = 0.25f*(a0*a0+a1*a1+a2*a2+a3*a3);
    float v = q - m*m;
    float s = g2[t]*rsqrtf(v + EPSBN);
    sc[t] = s; sh[t] = be2[t] - m*s;
  }
  __syncthreads();
  {
    const int o2 = t & 63;
    float z = wei[t]*sc[o2] + sh[o2];
    wei[t] = 1.0f/(1.0f + expf(-z));
  }
  __syncthreads();
}

// ---- K2: partials -> BN stats -> SE MLPs -> per-plane coefficients ----
__global__ __launch_bounds__(256) void se_kernel(
    const float* __restrict__ partials, int bpp,
    const float* __restrict__ bn1_g, const float* __restrict__ bn1_b,
    const float* __restrict__ bn2_g, const float* __restrict__ bn2_b,
    const float* __restrict__ td_w1, const float* __restrict__ td_b1,
    const float* __restrict__ td_g1, const float* __restrict__ td_be1,
    const float* __restrict__ td_w2, const float* __restrict__ td_b2,
    const float* __restrict__ td_g2, const float* __restrict__ td_be2,
    const float* __restrict__ bu_w1, const float* __restrict__ bu_b1,
    const float* __restrict__ bu_g1, const float* __restrict__ bu_be1,
    const float* __restrict__ bu_w2, const float* __restrict__ bu_b2,
    const float* __restrict__ bu_g2, const float* __restrict__ bu_be2,
    float* __restrict__ coef)
{
  __shared__ float sum13[256], sq13[256], sum17[256], sq17[256];
  __shared__ float scale1[64], shift1[64], scale2[64], shift2[64];
  __shared__ float pm13[256], pm17[256];
  __shared__ float y1[128], sc[64], sh[64];
  __shared__ float tdw[256], buw[256];
  const int t = threadIdx.x;

  {
    float a=0.f,b=0.f,c=0.f,d=0.f;
    for (int kb = 0; kb < bpp; ++kb) {
      const float* q = partials + ((size_t)(t*bpp + kb))*4;
      a += q[0]; b += q[1]; c += q[2]; d += q[3];
    }
    sum13[t]=a; sq13[t]=b; sum17[t]=c; sq17[t]=d;
  }
  __syncthreads();

  if (t < 64) {
    float s=0.f,q=0.f,s2=0.f,q2=0.f;
    for (int b = 0; b < 4; ++b) {
      s  += sum13[b*64+t]; q  += sq13[b*64+t];
      s2 += sum17[b*64+t]; q2 += sq17[b*64+t];
    }
    const float inv = 1.0f/(4.0f*HWSZ);
    float m1 = s*inv,  v1 = q*inv  - m1*m1;
    float c1 = bn1_g[t]*rsqrtf(v1 + EPSBN);
    scale1[t] = c1; shift1[t] = bn1_b[t] - m1*c1;
    float m2 = s2*inv, v2 = q2*inv - m2*m2;
    float c2 = bn2_g[t]*rsqrtf(v2 + EPSBN);
    scale2[t] = c2; shift2[t] = bn2_b[t] - m2*c2;
  }
  __syncthreads();

  {
    const int c = t & 63;
    pm13[t] = (sum13[t]*(1.0f/HWSZ))*scale1[c] + shift1[c];
    pm17[t] = (sum17[t]*(1.0f/HWSZ))*scale2[c] + shift2[c];
  }
  __syncthreads();

  se_mlp(t, pm17, td_w1, td_b1, td_g1, td_be1, td_w2, td_b2, td_g2, td_be2, y1, sc, sh, tdw);
  se_mlp(t, pm13, bu_w1, bu_b1, bu_g1, bu_be1, bu_w2, bu_b2, bu_g2, bu_be2, y1, sc, sh, buw);

  {
    const int c = t & 63;
    float A  = tdw[t]*scale1[c];
    float Bc = buw[t]*scale2[c];
    float Cc = tdw[t]*shift1[c] + buw[t]*shift2[c];
    coef[t*4+0] = A; coef[t*4+1] = Bc; coef[t*4+2] = Cc; coef[t*4+3] = 0.f;
  }
}

// ---- K3: elementwise combine from packed pcm (NT read/write) ----
#define K3_BLOCKS 4608
#define K3_THREADS 256

__global__ __launch_bounds__(K3_THREADS) void k3_kernel(const u4v* __restrict__ pcm4,
                                                        const f4v* __restrict__ coef4,
                                                        f4v* __restrict__ out4)
{
  const int total = NPLANES*HWSZ/4;           // 9,437,184
  int i = blockIdx.x*K3_THREADS + threadIdx.x;
  const int stride = K3_BLOCKS*K3_THREADS;
  for (; i < total; i += stride) {
    const int plane = (i*4)/HWSZ;             // 4 px always within one plane
    const f4v cf = coef4[plane];              // A,B,C,_
    const u4v v = __builtin_nontemporal_load(&pcm4[i]);
    f4v o;
    #pragma unroll
    for (int j = 0; j < 4; ++j) {
      unsigned int u = v[j];
      __half2 hp = *reinterpret_cast<__half2*>(&u);
      float2 f = __half22float2(hp);
      o[j] = cf.x*f.x + cf.y*f.y + cf.z;
    }
    __builtin_nontemporal_store(o, &out4[i]);
  }
}

// ================= fallback (small ws): two-pass recompute =================
__global__ __launch_bounds__(384) void passA_kernel(const float* __restrict__ cen,
                                                    float* __restrict__ partials)
{
  const int blk = swz_block<NB_FB>();
  const int p   = blk / BPP_FB;
  const int kb  = blk % BPP_FB;
  const int w   = threadIdx.x;
  const float* pp = cen + (size_t)p*HWSZ;

  int wp13 = w+13; if (wp13 >= WW) wp13 -= WW;
  int wm13 = w-13; if (wm13 <  0 ) wm13 += WW;
  int wp17 = w+17; if (wp17 >= WW) wp17 -= WW;
  int wm17 = w-17; if (wm17 <  0 ) wm17 += WW;

  float s13 = 0.f, q13 = 0.f, s17 = 0.f, q17 = 0.f;
  const int h0 = kb*ROWS_FB;
  for (int r = 0; r < ROWS_FB; r += 2) {
    float va[17], vb[17];
    pcm_loads(pp, h0+r,   w, wp13, wm13, wp17, wm17, va);
    pcm_loads(pp, h0+r+1, w, wp13, wm13, wp17, wm17, vb);
    __builtin_amdgcn_sched_barrier(0);
    float a13, a17, b13, b17;
    pcm_eval(va, a13, a17);
    pcm_eval(vb, b13, b17);
    s13 += a13 + b13; q13 += a13*a13 + b13*b13;
    s17 += a17 + b17; q17 += a17*a17 + b17*b17;
  }
  for (int off = 32; off > 0; off >>= 1) {
    s13 += __shfl_down(s13, off);
    q13 += __shfl_down(q13, off);
    s17 += __shfl_down(s17, off);
    q17 += __shfl_down(q17, off);
  }
  __shared__ float red[6][4];
  const int wid = threadIdx.x >> 6;
  if ((threadIdx.x & 63) == 0) {
    red[wid][0] = s13; red[wid][1] = q13; red[wid][2] = s17; red[wid][3] = q17;
  }
  __syncthreads();
  if (threadIdx.x == 0) {
    float a=0.f,b=0.f,c=0.f,d=0.f;
    for (int i = 0; i < 6; ++i) { a+=red[i][0]; b+=red[i][1]; c+=red[i][2]; d+=red[i][3]; }
    float* q = partials + (size_t)blk*4;
    q[0]=a; q[1]=b; q[2]=c; q[3]=d;
  }
}

__global__ __launch_bounds__(384) void passB_kernel(const float* __restrict__ cen,
                                                    const float* __restrict__ coef,
                                                    float* __restrict__ out)
{
  const int blk = swz_block<NB_FB>();
  const int p   = blk / BPP_FB;
  const int kb  = blk % BPP_FB;
  const int w   = threadIdx.x;
  const float A  = coef[p*4+0];
  const float Bc = coef[p*4+1];
  const float Cc = coef[p*4+2];
  const float* pp = cen + (size_t)p*HWSZ;
  float* op = out + (size_t)p*HWSZ;

  int wp13 = w+13; if (wp13 >= WW) wp13 -= WW;
  int wm13 = w-13; if (wm13 <  0 ) wm13 += WW;
  int wp17 = w+17; if (wp17 >= WW) wp17 -= WW;
  int wm17 = w-17; if (wm17 <  0 ) wm17 += WW;

  const int h0 = kb*ROWS_FB;
  for (int r = 0; r < ROWS_FB; r += 2) {
    const int h = h0 + r;
    float va[17], vb[17];
    pcm_loads(pp, h,   w, wp13, wm13, wp17, wm17, va);
    pcm_loads(pp, h+1, w, wp13, wm13, wp17, wm17, vb);
    __builtin_amdgcn_sched_barrier(0);
    float a13, a17, b13, b17;
    pcm_eval(va, a13, a17);
    pcm_eval(vb, b13, b17);
    __builtin_nontemporal_store(A*a13 + Bc*a17 + Cc, &op[h*WW + w]);
    __builtin_nontemporal_store(A*b13 + Bc*b17 + Cc, &op[(h+1)*WW + w]);
  }
}

extern "C" void kernel_launch(void* const* d_in, const int* in_sizes, int n_in,
                              void* d_out, int out_size, void* d_ws, size_t ws_size,
                              hipStream_t stream) {
  const float* cen = (const float*)d_in[0];
  const size_t PCM_BYTES = (size_t)NPLANES*HWSZ*sizeof(unsigned int);   // ~151 MB
  const size_t NEED = PCM_BYTES + (size_t)NB_K1*4*sizeof(float) + 256*4*sizeof(float);

  if (ws_size >= NEED) {
    unsigned int* pcm_ws = (unsigned int*)d_ws;
    float* partials = (float*)((char*)d_ws + PCM_BYTES);
    float* coef     = partials + (size_t)NB_K1*4;

    k1_kernel<<<NB_K1, 384, 0, stream>>>(cen, pcm_ws, partials);
    se_kernel<<<1, 256, 0, stream>>>(partials, BPP_K1,
        (const float*)d_in[1],  (const float*)d_in[2],  (const float*)d_in[3],  (const float*)d_in[4],
        (const float*)d_in[5],  (const float*)d_in[6],  (const float*)d_in[7],  (const float*)d_in[8],
        (const float*)d_in[9],  (const float*)d_in[10], (const float*)d_in[11], (const float*)d_in[12],
        (const float*)d_in[13], (const float*)d_in[14], (const float*)d_in[15], (const float*)d_in[16],
        (const float*)d_in[17], (const float*)d_in[18], (const float*)d_in[19], (const float*)d_in[20],
        coef);
    k3_kernel<<<K3_BLOCKS, K3_THREADS, 0, stream>>>((const u4v*)pcm_ws, (const f4v*)coef, (f4v*)d_out);
  } else {
    float* ws = (float*)d_ws;
    float* partials = ws;
    float* coef     = ws + (size_t)NB_FB*4;
    passA_kernel<<<NB_FB, 384, 0, stream>>>(cen, partials);
    se_kernel<<<1, 256, 0, stream>>>(partials, BPP_FB,
        (const float*)d_in[1],  (const float*)d_in[2],  (const float*)d_in[3],  (const float*)d_in[4],
        (const float*)d_in[5],  (const float*)d_in[6],  (const float*)d_in[7],  (const float*)d_in[8],
        (const float*)d_in[9],  (const float*)d_in[10], (const float*)d_in[11], (const float*)d_in[12],
        (const float*)d_in[13], (const float*)d_in[14], (const float*)d_in[15], (const float*)d_in[16],
        (const float*)d_in[17], (const float*)d_in[18], (const float*)d_in[19], (const float*)d_in[20],
        coef);
    passB_kernel<<<NB_FB, 384, 0, stream>>>(cen, coef, (float*)d_out);
  }
}